// Round 3
// baseline (1803.509 us; speedup 1.0000x reference)
//
#include <hip/hip_runtime.h>
#include <hip/hip_bf16.h>

#define BB 8
#define CC 512
#define TT 1024
#define HH 8
#define HD 64
#define CLIPW 4
#define NCOUT 512

using bf16 = __hip_bfloat16;

__device__ __forceinline__ float bf2f(bf16 v) {
  return __uint_as_float(((unsigned int)*(unsigned short*)&v) << 16);
}
// 8 contiguous bf16 -> 8 floats (one 16B load)
__device__ __forceinline__ void ld8bf(const bf16* p, float* o) {
  const uint4 u = *(const uint4*)p;
  o[0] = __uint_as_float(u.x << 16); o[1] = __uint_as_float(u.x & 0xffff0000u);
  o[2] = __uint_as_float(u.y << 16); o[3] = __uint_as_float(u.y & 0xffff0000u);
  o[4] = __uint_as_float(u.z << 16); o[5] = __uint_as_float(u.z & 0xffff0000u);
  o[6] = __uint_as_float(u.w << 16); o[7] = __uint_as_float(u.w & 0xffff0000u);
}

// ---------------------------------------------------------------------------
// K1: one projection.  dst[b,h,t,d] = sum_c W[h*64+d,c] X[b,c,t] + bias  (bf16)
// ---------------------------------------------------------------------------
__global__ __launch_bounds__(256) void proj_one(
    const float* __restrict__ X, const float* __restrict__ W,
    const float* __restrict__ bias, bf16* __restrict__ dst) {
  __shared__ float Xs[64][65];
  __shared__ float Ws[64][65];
  const int b  = blockIdx.z;
  const int o0 = blockIdx.y * 64;
  const int t0 = blockIdx.x * 64;
  const int tid = threadIdx.x;
  const int tj  = tid & 63;
  const int ti4 = tid >> 6;
  const int to  = (tid >> 4) << 2;
  const int tt  = (tid & 15) << 2;

  float acc[4][4] = {};
  for (int c0 = 0; c0 < CC; c0 += 64) {
    for (int i = ti4; i < 64; i += 4) {
      Xs[i][tj] = X[((size_t)b * CC + c0 + i) * TT + t0 + tj];
      Ws[i][tj] = W[(size_t)(o0 + i) * CC + c0 + tj];
    }
    __syncthreads();
    for (int kk = 0; kk < 64; ++kk) {
      float wr[4], xr[4];
#pragma unroll
      for (int i = 0; i < 4; ++i) wr[i] = Ws[to + i][kk];
#pragma unroll
      for (int j = 0; j < 4; ++j) xr[j] = Xs[kk][tt + j];
#pragma unroll
      for (int i = 0; i < 4; ++i)
#pragma unroll
        for (int j = 0; j < 4; ++j) acc[i][j] += wr[i] * xr[j];
    }
    __syncthreads();
  }
#pragma unroll
  for (int i = 0; i < 4; ++i) {
    const int o = o0 + to + i;
    const int h = o >> 6, d = o & 63;
    const float bv_ = bias[o];
#pragma unroll
    for (int j = 0; j < 4; ++j) {
      const int t = t0 + tt + j;
      dst[(((size_t)b * HH + h) * TT + t) * HD + d] = __float2bfloat16(acc[i][j] + bv_);
    }
  }
}

// ---------------------------------------------------------------------------
// K2: fused attention row.  One block per (b,h,t).
//   scores -> softmax -> fp32 alignments out -> PV + band value bias -> bf16 attn
// ---------------------------------------------------------------------------
__global__ __launch_bounds__(256) void attn_row(
    const bf16* __restrict__ qw, const bf16* __restrict__ kw,
    const bf16* __restrict__ vw,
    const float* __restrict__ wK, const float* __restrict__ wV,
    float* __restrict__ align_out, bf16* __restrict__ attnw) {
  const int t  = blockIdx.x;
  const int h  = blockIdx.y;
  const int b  = blockIdx.z;
  const int bh = b * HH + h;
  const int tid = threadIdx.x;
  const float scale = 0.125f;

  __shared__ float qs[HD];
  __shared__ float sc[TT];
  __shared__ float red[256];

  if (tid < HD) qs[tid] = bf2f(qw[((size_t)bh * TT + t) * HD + tid]);
  __syncthreads();

  // --- scores ---
  for (int s = tid; s < TT; s += 256) {
    const bf16* krow = kw + ((size_t)bh * TT + s) * HD;
    float acc = 0.f;
#pragma unroll
    for (int d8 = 0; d8 < 8; ++d8) {
      float kv[8];
      ld8bf(krow + d8 * 8, kv);
#pragma unroll
      for (int j = 0; j < 8; ++j) acc += qs[d8 * 8 + j] * kv[j];
    }
    const int delta = s - t;
    if (delta >= -CLIPW && delta <= CLIPW) {
      const float* wkr = wK + (size_t)(delta + CLIPW) * HD;
      float r = 0.f;
#pragma unroll
      for (int d = 0; d < HD; ++d) r += qs[d] * wkr[d];
      acc += r;
    }
    sc[s] = acc * scale;
  }
  __syncthreads();

  // --- max reduce ---
  float mx = -1e30f;
  for (int s = tid; s < TT; s += 256) mx = fmaxf(mx, sc[s]);
  red[tid] = mx;
  __syncthreads();
  for (int w = 128; w >= 1; w >>= 1) {
    if (tid < w) red[tid] = fmaxf(red[tid], red[tid + w]);
    __syncthreads();
  }
  mx = red[0];
  __syncthreads();

  // --- exp + sum ---
  float lsum = 0.f;
  for (int s = tid; s < TT; s += 256) {
    const float e = __expf(sc[s] - mx);
    sc[s] = e;
    lsum += e;
  }
  red[tid] = lsum;
  __syncthreads();
  for (int w = 128; w >= 1; w >>= 1) {
    if (tid < w) red[tid] += red[tid + w];
    __syncthreads();
  }
  const float inv = 1.0f / red[0];
  __syncthreads();   // protect red[0] before reuse below

  // --- write alignments (fp32, coalesced in s) ---
  for (int s = tid; s < TT; s += 256) {
    align_out[((size_t)bh * TT + t) * TT + s] = sc[s] * inv;
  }

  // --- PV: 4 s-groups x 64 d ---
  const int d  = tid & 63;
  const int sg = tid >> 6;
  float pacc = 0.f;
  const bf16* vbase = vw + ((size_t)bh * TT + sg * 256) * HD + d;
  for (int s = 0; s < 256; ++s) pacc += sc[sg * 256 + s] * bf2f(vbase[(size_t)s * HD]);
  red[tid] = pacc;
  __syncthreads();

  if (tid < 64) {
    float a = red[tid] + red[tid + 64] + red[tid + 128] + red[tid + 192];
#pragma unroll
    for (int r = 0; r < 2 * CLIPW + 1; ++r) {
      const int s2 = t + r - CLIPW;
      if (s2 >= 0 && s2 < TT) a += sc[s2] * wV[r * HD + tid];
    }
    a *= inv;
    attnw[((size_t)b * CC + h * HD + tid) * TT + t] = __float2bfloat16(a);
  }
}

// ---------------------------------------------------------------------------
// K3: output projection. out[b,o,t] = bp[o] + sum_c Wp[o,c] attn[b,c,t] (fp32)
// ---------------------------------------------------------------------------
__global__ __launch_bounds__(256) void out_proj(
    const bf16* __restrict__ A, const float* __restrict__ Wp,
    const float* __restrict__ bp, float* __restrict__ out) {
  __shared__ float As[64][65];
  __shared__ float Ws[64][65];
  const int b  = blockIdx.z;
  const int o0 = blockIdx.y * 64;
  const int t0 = blockIdx.x * 64;
  const int tid = threadIdx.x;
  const int tj  = tid & 63;
  const int ti4 = tid >> 6;
  const int to  = (tid >> 4) << 2;
  const int tt  = (tid & 15) << 2;

  float acc[4][4] = {};
  for (int c0 = 0; c0 < CC; c0 += 64) {
    for (int i = ti4; i < 64; i += 4) {
      As[i][tj] = bf2f(A[((size_t)b * CC + c0 + i) * TT + t0 + tj]);
      Ws[i][tj] = Wp[(size_t)(o0 + i) * CC + c0 + tj];
    }
    __syncthreads();
    for (int kk = 0; kk < 64; ++kk) {
      float wr[4], xr[4];
#pragma unroll
      for (int i = 0; i < 4; ++i) wr[i] = Ws[to + i][kk];
#pragma unroll
      for (int j = 0; j < 4; ++j) xr[j] = As[kk][tt + j];
#pragma unroll
      for (int i = 0; i < 4; ++i)
#pragma unroll
        for (int j = 0; j < 4; ++j) acc[i][j] += wr[i] * xr[j];
    }
    __syncthreads();
  }
#pragma unroll
  for (int i = 0; i < 4; ++i) {
    const int o = o0 + to + i;
    const float bv_ = bp[o];
#pragma unroll
    for (int j = 0; j < 4; ++j) {
      const int t = t0 + tt + j;
      out[((size_t)b * NCOUT + o) * TT + t] = acc[i][j] + bv_;
    }
  }
}

extern "C" void kernel_launch(void* const* d_in, const int* in_sizes, int n_in,
                              void* d_out, int out_size, void* d_ws, size_t ws_size,
                              hipStream_t stream) {
  const float* X  = (const float*)d_in[0];
  const float* Wq = (const float*)d_in[1];
  const float* bq = (const float*)d_in[2];
  const float* Wk = (const float*)d_in[3];
  const float* bk = (const float*)d_in[4];
  const float* Wv = (const float*)d_in[5];
  const float* bv = (const float*)d_in[6];
  const float* Wp = (const float*)d_in[7];
  const float* bp = (const float*)d_in[8];
  const float* wK = (const float*)d_in[9];
  const float* wV = (const float*)d_in[10];

  float* out       = (float*)d_out;
  float* align_out = out + (size_t)BB * NCOUT * TT;       // 4,194,304 floats in

  const size_t SZ = (size_t)BB * HH * TT * HD;            // 4,194,304 elems
  bf16* qw    = (bf16*)d_ws;                              // 8 MiB
  bf16* kw    = qw + SZ;                                  // 8 MiB
  bf16* vw    = qw + 2 * SZ;                              // 8 MiB
  bf16* attnw = qw + 3 * SZ;                              // 8 MiB (total 32 MiB)

  const dim3 gProj(TT / 64, CC / 64, BB);
  const dim3 gAttn(TT, HH, BB);
  const dim3 gOut(TT / 64, NCOUT / 64, BB);

  proj_one<<<gProj, 256, 0, stream>>>(X, Wq, bq, qw);
  proj_one<<<gProj, 256, 0, stream>>>(X, Wk, bk, kw);
  proj_one<<<gProj, 256, 0, stream>>>(X, Wv, bv, vw);
  attn_row<<<gAttn, 256, 0, stream>>>(qw, kw, vw, wK, wV, align_out, attnw);
  out_proj<<<gOut, 256, 0, stream>>>(attnw, Wp, bp, out);
}

// Round 4
// 571.843 us; speedup vs baseline: 3.1539x; 3.1539x over previous
//
#include <hip/hip_runtime.h>
#include <hip/hip_bf16.h>

#define BB 8
#define CC 512
#define TT 1024
#define HH 8
#define HD 64
#define CLIPW 4
#define NCOUT 512

using bf16 = __hip_bfloat16;
typedef __bf16 bf16x8_t __attribute__((ext_vector_type(8)));
typedef float f32x4_t __attribute__((ext_vector_type(4)));

__device__ __forceinline__ float bf2f(bf16 v) {
  return __uint_as_float(((unsigned int)*(unsigned short*)&v) << 16);
}

// ---------------------------------------------------------------------------
// K1: one projection.  acc = W @ X + bias.
// VT=false: dst[b][h][t][d] (row-per-t, for Q/K)
// VT=true : dst[b][c][t]    (row-per-c, for V^T / attn-style layout)
// ---------------------------------------------------------------------------
template <bool VT>
__global__ __launch_bounds__(256) void proj_one(
    const float* __restrict__ X, const float* __restrict__ W,
    const float* __restrict__ bias, bf16* __restrict__ dst) {
  __shared__ float Xs[64][65];
  __shared__ float Ws[64][65];
  const int b  = blockIdx.z;
  const int o0 = blockIdx.y * 64;
  const int t0 = blockIdx.x * 64;
  const int tid = threadIdx.x;
  const int tj  = tid & 63;
  const int ti4 = tid >> 6;
  const int to  = (tid >> 4) << 2;
  const int tt  = (tid & 15) << 2;

  float acc[4][4] = {};
  for (int c0 = 0; c0 < CC; c0 += 64) {
    for (int i = ti4; i < 64; i += 4) {
      Xs[i][tj] = X[((size_t)b * CC + c0 + i) * TT + t0 + tj];
      Ws[i][tj] = W[(size_t)(o0 + i) * CC + c0 + tj];
    }
    __syncthreads();
    for (int kk = 0; kk < 64; ++kk) {
      float wr[4], xr[4];
#pragma unroll
      for (int i = 0; i < 4; ++i) wr[i] = Ws[to + i][kk];
#pragma unroll
      for (int j = 0; j < 4; ++j) xr[j] = Xs[kk][tt + j];
#pragma unroll
      for (int i = 0; i < 4; ++i)
#pragma unroll
        for (int j = 0; j < 4; ++j) acc[i][j] += wr[i] * xr[j];
    }
    __syncthreads();
  }
#pragma unroll
  for (int i = 0; i < 4; ++i) {
    const int o = o0 + to + i;
    const float bv_ = bias[o];
#pragma unroll
    for (int j = 0; j < 4; ++j) {
      const int t = t0 + tt + j;
      if (VT) {
        dst[((size_t)b * CC + o) * TT + t] = __float2bfloat16(acc[i][j] + bv_);
      } else {
        dst[(((size_t)b * HH + (o >> 6)) * TT + t) * HD + (o & 63)] =
            __float2bfloat16(acc[i][j] + bv_);
      }
    }
  }
}

// ---------------------------------------------------------------------------
// K2: MFMA attention.  One block = 16 q-rows (QBLK), 4 waves; wave w owns
// s-range [256w, 256w+256).  mfma_f32_16x16x32_bf16 layouts:
//   A: row=lane&15, k=(lane>>4)*8+j   B: col=lane&15, k=(lane>>4)*8+j
//   D: col=lane&15, row=(lane>>4)*4+reg
// ---------------------------------------------------------------------------
__global__ __launch_bounds__(256) void attn_mfma(
    const bf16* __restrict__ qw, const bf16* __restrict__ kw,
    const bf16* __restrict__ vtw,
    const float* __restrict__ wK, const float* __restrict__ wV,
    float* __restrict__ align_out, bf16* __restrict__ attnw) {
  const int q0 = blockIdx.x * 16;
  const int h  = blockIdx.y;
  const int b  = blockIdx.z;
  const int bh = b * HH + h;
  const int tid = threadIdx.x;
  const int w  = tid >> 6;
  const int l  = tid & 63;
  const int g  = l >> 4;
  const int sl = l & 15;

  __shared__ float bandv[16][9];     // Q . wK[j] raw dots
  __shared__ float bandP[16][9];     // normalized in-band P
  __shared__ float redbuf[4][16];    // softmax cross-wave stats
  __shared__ float tbuf[4][16][36];  // per-wave P transpose (fp32, pad 36)
  __shared__ float obuf[4][16][68];  // per-wave PV partials (pad 68)

  // phase 0: band-K dots + bandP init
  if (tid < 144) {
    const int q = tid / 9, j = tid % 9;
    const bf16* qrow = qw + ((size_t)bh * TT + q0 + q) * HD;
    const float* wkr = wK + j * HD;
    float s = 0.f;
    for (int d = 0; d < HD; ++d) s += bf2f(qrow[d]) * wkr[d];
    bandv[q][j] = s;
    bandP[q][j] = 0.f;
  }

  // Q A-frags (row sl, k halves)
  const bf16* qbase = qw + ((size_t)bh * TT + q0 + sl) * HD + g * 8;
  const bf16x8_t qa0 = *(const bf16x8_t*)(qbase);
  const bf16x8_t qa1 = *(const bf16x8_t*)(qbase + 32);

  __syncthreads();

  // --- QK^T ---
  f32x4_t acc[16];
#pragma unroll
  for (int t2 = 0; t2 < 16; ++t2) acc[t2] = (f32x4_t){0.f, 0.f, 0.f, 0.f};
  const int sbase = w * 256;
#pragma unroll
  for (int t2 = 0; t2 < 16; ++t2) {
    const bf16* kb = kw + ((size_t)bh * TT + sbase + t2 * 16 + sl) * HD + g * 8;
    const bf16x8_t k0 = *(const bf16x8_t*)(kb);
    const bf16x8_t k1 = *(const bf16x8_t*)(kb + 32);
    acc[t2] = __builtin_amdgcn_mfma_f32_16x16x32_bf16(qa0, k0, acc[t2], 0, 0, 0);
    acc[t2] = __builtin_amdgcn_mfma_f32_16x16x32_bf16(qa1, k1, acc[t2], 0, 0, 0);
  }

  // --- scale + band-K bias ---
#pragma unroll
  for (int t2 = 0; t2 < 16; ++t2) {
    const int s0t = sbase + t2 * 16;
    const bool bandpos = (s0t + 15 >= q0 - CLIPW) && (s0t <= q0 + 15 + CLIPW);
#pragma unroll
    for (int r = 0; r < 4; ++r) {
      float v2 = acc[t2][r];
      if (bandpos) {
        const int qv = 4 * g + r;
        const int delta = (s0t + sl) - (q0 + qv);
        if (delta >= -CLIPW && delta <= CLIPW) v2 += bandv[qv][delta + CLIPW];
      }
      acc[t2][r] = v2 * 0.125f;
    }
  }

  // --- softmax: row max ---
  float mrow[4];
#pragma unroll
  for (int r = 0; r < 4; ++r) {
    float mv = acc[0][r];
#pragma unroll
    for (int t2 = 1; t2 < 16; ++t2) mv = fmaxf(mv, acc[t2][r]);
#pragma unroll
    for (int d2 = 1; d2 < 16; d2 <<= 1) mv = fmaxf(mv, __shfl_xor(mv, d2));
    mrow[r] = mv;
  }
  if (sl == 0) {
#pragma unroll
    for (int r = 0; r < 4; ++r) redbuf[w][4 * g + r] = mrow[r];
  }
  __syncthreads();
#pragma unroll
  for (int r = 0; r < 4; ++r) {
    float mv = fmaxf(fmaxf(redbuf[0][4 * g + r], redbuf[1][4 * g + r]),
                     fmaxf(redbuf[2][4 * g + r], redbuf[3][4 * g + r]));
    mrow[r] = mv;
  }

  // --- exp + row sum ---
  float srow[4] = {0.f, 0.f, 0.f, 0.f};
#pragma unroll
  for (int t2 = 0; t2 < 16; ++t2) {
#pragma unroll
    for (int r = 0; r < 4; ++r) {
      const float e = __expf(acc[t2][r] - mrow[r]);
      acc[t2][r] = e;
      srow[r] += e;
    }
  }
#pragma unroll
  for (int r = 0; r < 4; ++r) {
#pragma unroll
    for (int d2 = 1; d2 < 16; d2 <<= 1) srow[r] += __shfl_xor(srow[r], d2);
  }
  __syncthreads();  // protect redbuf (max) until everyone has read it
  if (sl == 0) {
#pragma unroll
    for (int r = 0; r < 4; ++r) redbuf[w][4 * g + r] = srow[r];
  }
  __syncthreads();
  float inv[4];
#pragma unroll
  for (int r = 0; r < 4; ++r) {
    inv[r] = 1.0f / (redbuf[0][4 * g + r] + redbuf[1][4 * g + r] +
                     redbuf[2][4 * g + r] + redbuf[3][4 * g + r]);
  }

  // --- normalize, write alignments (fp32), stash band P ---
  float* abase = align_out + ((size_t)bh * TT + q0) * TT + sbase + sl;
#pragma unroll
  for (int t2 = 0; t2 < 16; ++t2) {
    const int s0t = sbase + t2 * 16;
    const bool bandpos = (s0t + 15 >= q0 - CLIPW) && (s0t <= q0 + 15 + CLIPW);
#pragma unroll
    for (int r = 0; r < 4; ++r) {
      const int qv = 4 * g + r;
      const float p = acc[t2][r] * inv[r];
      acc[t2][r] = p;
      abase[(size_t)qv * TT + t2 * 16] = p;
      if (bandpos) {
        const int delta = (s0t + sl) - (q0 + qv);
        if (delta >= -CLIPW && delta <= CLIPW) bandP[qv][delta + CLIPW] = p;
      }
    }
  }

  // --- PV: per-wave transpose 32-s chunks of P through LDS, MFMA with V^T ---
  f32x4_t oacc[4];
#pragma unroll
  for (int dt = 0; dt < 4; ++dt) oacc[dt] = (f32x4_t){0.f, 0.f, 0.f, 0.f};
  float(*tb)[36] = tbuf[w];
#pragma unroll
  for (int cp = 0; cp < 8; ++cp) {
#pragma unroll
    for (int t2 = 0; t2 < 2; ++t2) {
#pragma unroll
      for (int r = 0; r < 4; ++r) tb[4 * g + r][t2 * 16 + sl] = acc[cp * 2 + t2][r];
    }
    __asm__ volatile("s_waitcnt lgkmcnt(0)" ::: "memory");
    __builtin_amdgcn_sched_barrier(0);
    const f32x4_t pa0 = *(const f32x4_t*)&tb[sl][g * 8];
    const f32x4_t pa1 = *(const f32x4_t*)&tb[sl][g * 8 + 4];
    bf16x8_t pa;
#pragma unroll
    for (int i2 = 0; i2 < 4; ++i2) {
      pa[i2]     = (__bf16)pa0[i2];
      pa[4 + i2] = (__bf16)pa1[i2];
    }
    const bf16* vb = vtw + ((size_t)bh * HD + sl) * TT + sbase + cp * 32 + g * 8;
#pragma unroll
    for (int dt = 0; dt < 4; ++dt) {
      const bf16x8_t vf = *(const bf16x8_t*)(vb + (size_t)dt * 16 * TT);
      oacc[dt] = __builtin_amdgcn_mfma_f32_16x16x32_bf16(pa, vf, oacc[dt], 0, 0, 0);
    }
  }

  // --- cross-wave PV reduce + band-V bias + store attn [b][c][t] bf16 ---
#pragma unroll
  for (int dt = 0; dt < 4; ++dt)
#pragma unroll
    for (int r = 0; r < 4; ++r) obuf[w][4 * g + r][dt * 16 + sl] = oacc[dt][r];
  __syncthreads();

  const int q2 = tid & 15;
  const int d0 = tid >> 4;
#pragma unroll
  for (int rep = 0; rep < 4; ++rep) {
    const int d2 = d0 + rep * 16;
    float o = obuf[0][q2][d2] + obuf[1][q2][d2] + obuf[2][q2][d2] + obuf[3][q2][d2];
#pragma unroll
    for (int j = 0; j < 9; ++j) o += bandP[q2][j] * wV[j * HD + d2];
    attnw[((size_t)b * CC + h * HD + d2) * TT + q0 + q2] = __float2bfloat16(o);
  }
}

// ---------------------------------------------------------------------------
// K3: output projection. out[b,o,t] = bp[o] + sum_c Wp[o,c] attn[b,c,t] (fp32)
// ---------------------------------------------------------------------------
__global__ __launch_bounds__(256) void out_proj(
    const bf16* __restrict__ A, const float* __restrict__ Wp,
    const float* __restrict__ bp, float* __restrict__ out) {
  __shared__ float As[64][65];
  __shared__ float Ws[64][65];
  const int b  = blockIdx.z;
  const int o0 = blockIdx.y * 64;
  const int t0 = blockIdx.x * 64;
  const int tid = threadIdx.x;
  const int tj  = tid & 63;
  const int ti4 = tid >> 6;
  const int to  = (tid >> 4) << 2;
  const int tt  = (tid & 15) << 2;

  float acc[4][4] = {};
  for (int c0 = 0; c0 < CC; c0 += 64) {
    for (int i = ti4; i < 64; i += 4) {
      As[i][tj] = bf2f(A[((size_t)b * CC + c0 + i) * TT + t0 + tj]);
      Ws[i][tj] = Wp[(size_t)(o0 + i) * CC + c0 + tj];
    }
    __syncthreads();
    for (int kk = 0; kk < 64; ++kk) {
      float wr[4], xr[4];
#pragma unroll
      for (int i = 0; i < 4; ++i) wr[i] = Ws[to + i][kk];
#pragma unroll
      for (int j = 0; j < 4; ++j) xr[j] = As[kk][tt + j];
#pragma unroll
      for (int i = 0; i < 4; ++i)
#pragma unroll
        for (int j = 0; j < 4; ++j) acc[i][j] += wr[i] * xr[j];
    }
    __syncthreads();
  }
#pragma unroll
  for (int i = 0; i < 4; ++i) {
    const int o = o0 + to + i;
    const float bv_ = bp[o];
#pragma unroll
    for (int j = 0; j < 4; ++j) {
      const int t = t0 + tt + j;
      out[((size_t)b * NCOUT + o) * TT + t] = acc[i][j] + bv_;
    }
  }
}

extern "C" void kernel_launch(void* const* d_in, const int* in_sizes, int n_in,
                              void* d_out, int out_size, void* d_ws, size_t ws_size,
                              hipStream_t stream) {
  const float* X  = (const float*)d_in[0];
  const float* Wq = (const float*)d_in[1];
  const float* bq = (const float*)d_in[2];
  const float* Wk = (const float*)d_in[3];
  const float* bk = (const float*)d_in[4];
  const float* Wv = (const float*)d_in[5];
  const float* bv = (const float*)d_in[6];
  const float* Wp = (const float*)d_in[7];
  const float* bp = (const float*)d_in[8];
  const float* wK = (const float*)d_in[9];
  const float* wV = (const float*)d_in[10];

  float* out       = (float*)d_out;
  float* align_out = out + (size_t)BB * NCOUT * TT;

  const size_t SZ = (size_t)BB * HH * TT * HD;   // 4,194,304 elems
  bf16* qw    = (bf16*)d_ws;                     // 8 MiB  [b][h][t][d]
  bf16* kw    = qw + SZ;                         // 8 MiB  [b][h][t][d]
  bf16* vtw   = qw + 2 * SZ;                     // 8 MiB  [b][c][t]  (V^T)
  bf16* attnw = qw + 3 * SZ;                     // 8 MiB  [b][c][t]

  const dim3 gProj(TT / 64, CC / 64, BB);
  const dim3 gAttn(TT / 16, HH, BB);
  const dim3 gOut(TT / 64, NCOUT / 64, BB);

  proj_one<false><<<gProj, 256, 0, stream>>>(X, Wq, bq, qw);
  proj_one<false><<<gProj, 256, 0, stream>>>(X, Wk, bk, kw);
  proj_one<true><<<gProj, 256, 0, stream>>>(X, Wv, bv, vtw);
  attn_mfma<<<gAttn, 256, 0, stream>>>(qw, kw, vtw, wK, wV, align_out, attnw);
  out_proj<<<gOut, 256, 0, stream>>>(attnw, Wp, bp, out);
}

// Round 5
// 348.229 us; speedup vs baseline: 5.1791x; 1.6421x over previous
//
#include <hip/hip_runtime.h>
#include <hip/hip_bf16.h>

#define BB 8
#define CC 512
#define TT 1024
#define HH 8
#define HD 64
#define CLIPW 4
#define NCOUT 512

using bf16 = __hip_bfloat16;
typedef __bf16 bf16x8_t __attribute__((ext_vector_type(8)));
typedef __bf16 bf16x4_t __attribute__((ext_vector_type(4)));
typedef float f32x4_t __attribute__((ext_vector_type(4)));

__device__ __forceinline__ float bf2f(bf16 v) {
  return __uint_as_float(((unsigned int)*(unsigned short*)&v) << 16);
}

// ===========================================================================
// GEMM core geometry (both gemm kernels):
//   block tile 64(o) x 64(t), K=512 in 8 tiles of 64. 4 waves in 2x2 grid,
//   each wave 32x32 via 2x2 mfma_f32_16x16x32_bf16 frags.
//   A = W row-major [o][c] (LDS stride 72), B = X transposed [t][c] (stride 72).
//   D: row(=o) = 4*(lane>>4)+reg, col(=t) = lane&15.
//   Epilogue stages C through LDS for coalesced, layout-specific stores.
// ===========================================================================

// ---- fused q/k/v projection: blockIdx.y in 0..23 -> {q,k,v} x 8 o-tiles ----
__global__ __launch_bounds__(256) void gemm_qkv(
    const float* __restrict__ X,
    const float* __restrict__ Wq, const float* __restrict__ bq,
    const float* __restrict__ Wk, const float* __restrict__ bk,
    const float* __restrict__ Wv, const float* __restrict__ bv,
    bf16* __restrict__ qw, bf16* __restrict__ kw, bf16* __restrict__ vtw) {
  __shared__ __align__(16) char smem[2 * 64 * 72 * 2];   // Ws + Xs (18.4 KB)
  __bf16* Ws = (__bf16*)smem;
  __bf16* Xs = (__bf16*)(smem + 64 * 72 * 2);

  const int y  = blockIdx.y;
  const int m  = y >> 3;                 // 0=q 1=k 2=v
  const int o0 = (y & 7) * 64;
  const int t0 = blockIdx.x * 64;
  const int b  = blockIdx.z;
  const float* W    = (m == 0) ? Wq : (m == 1) ? Wk : Wv;
  const float* bias = (m == 0) ? bq : (m == 1) ? bk : bv;

  const int tid = threadIdx.x;
  const int w = tid >> 6, l = tid & 63, g = l >> 4, sl = l & 15;
  const int wr = w >> 1, wc = w & 1;

  f32x4_t acc[2][2] = {};
  for (int c0 = 0; c0 < CC; c0 += 64) {
    {  // stage W tile (fp32 -> bf16)
      const int oi = tid >> 4, c4 = (tid & 15) * 4;
#pragma unroll
      for (int op = 0; op < 4; ++op) {
        const int o = op * 16 + oi;
        const float4 w4 = *(const float4*)&W[(size_t)(o0 + o) * CC + c0 + c4];
        bf16x4_t p;
        p[0] = (__bf16)w4.x; p[1] = (__bf16)w4.y;
        p[2] = (__bf16)w4.z; p[3] = (__bf16)w4.w;
        *(bf16x4_t*)&Ws[o * 72 + c4] = p;
      }
    }
    {  // stage X tile transposed: Xs[t][c]
      const int t4 = (tid & 15) * 4, ci = tid >> 4;
#pragma unroll
      for (int cp = 0; cp < 4; ++cp) {
        const int c = cp * 16 + ci;
        const float4 x4 = *(const float4*)&X[((size_t)b * CC + c0 + c) * TT + t0 + t4];
        Xs[(t4 + 0) * 72 + c] = (__bf16)x4.x;
        Xs[(t4 + 1) * 72 + c] = (__bf16)x4.y;
        Xs[(t4 + 2) * 72 + c] = (__bf16)x4.z;
        Xs[(t4 + 3) * 72 + c] = (__bf16)x4.w;
      }
    }
    __syncthreads();
#pragma unroll
    for (int kk = 0; kk < 2; ++kk) {
      bf16x8_t a[2], bb[2];
#pragma unroll
      for (int mm = 0; mm < 2; ++mm)
        a[mm] = *(const bf16x8_t*)&Ws[(wr * 32 + mm * 16 + sl) * 72 + kk * 32 + g * 8];
#pragma unroll
      for (int nn = 0; nn < 2; ++nn)
        bb[nn] = *(const bf16x8_t*)&Xs[(wc * 32 + nn * 16 + sl) * 72 + kk * 32 + g * 8];
#pragma unroll
      for (int mm = 0; mm < 2; ++mm)
#pragma unroll
        for (int nn = 0; nn < 2; ++nn)
          acc[mm][nn] = __builtin_amdgcn_mfma_f32_16x16x32_bf16(a[mm], bb[nn], acc[mm][nn], 0, 0, 0);
    }
    __syncthreads();
  }

  // epilogue: stage C in LDS (reuse smem), then coalesced store
  float* Cs = (float*)smem;   // 64x68 fp32 = 17.4 KB <= 18.4
#pragma unroll
  for (int mm = 0; mm < 2; ++mm)
#pragma unroll
    for (int nn = 0; nn < 2; ++nn)
#pragma unroll
      for (int r = 0; r < 4; ++r)
        Cs[(wr * 32 + mm * 16 + 4 * g + r) * 68 + wc * 32 + nn * 16 + sl] = acc[mm][nn][r];
  __syncthreads();

  if (m < 2) {
    // qk layout: dst[((b*8+h)*1024 + t)*64 + d], h = o0>>6, d = o_local
    bf16* dst = (m == 0) ? qw : kw;
    const int hh2 = o0 >> 6;
    const int t = tid >> 2, oq = tid & 3;
    bf16x8_t p0, p1;
#pragma unroll
    for (int i = 0; i < 8; ++i) {
      p0[i] = (__bf16)(Cs[(oq * 16 + i) * 68 + t] + bias[o0 + oq * 16 + i]);
      p1[i] = (__bf16)(Cs[(oq * 16 + 8 + i) * 68 + t] + bias[o0 + oq * 16 + 8 + i]);
    }
    bf16* dp = dst + (((size_t)b * HH + hh2) * TT + t0 + t) * HD + oq * 16;
    *(bf16x8_t*)dp = p0;
    *(bf16x8_t*)(dp + 8) = p1;
  } else {
    // v^T layout: dst[(b*512 + o)*1024 + t]
    const int o = tid >> 2, tq = tid & 3;
    const float bv_ = bias[o0 + o];
    bf16x8_t p0, p1;
#pragma unroll
    for (int i = 0; i < 8; ++i) {
      p0[i] = (__bf16)(Cs[o * 68 + tq * 16 + i] + bv_);
      p1[i] = (__bf16)(Cs[o * 68 + tq * 16 + 8 + i] + bv_);
    }
    bf16* dp = vtw + ((size_t)b * CC + o0 + o) * TT + t0 + tq * 16;
    *(bf16x8_t*)dp = p0;
    *(bf16x8_t*)(dp + 8) = p1;
  }
}

// ---- output projection: src attnw bf16 [c][t], out fp32 [o][t] ----
__global__ __launch_bounds__(256) void gemm_out(
    const bf16* __restrict__ S, const float* __restrict__ Wp,
    const float* __restrict__ bp, float* __restrict__ out) {
  __shared__ __align__(16) char smem[2 * 64 * 72 * 2];
  __bf16* Ws = (__bf16*)smem;
  __bf16* Xs = (__bf16*)(smem + 64 * 72 * 2);

  const int o0 = blockIdx.y * 64;
  const int t0 = blockIdx.x * 64;
  const int b  = blockIdx.z;
  const int tid = threadIdx.x;
  const int w = tid >> 6, l = tid & 63, g = l >> 4, sl = l & 15;
  const int wr = w >> 1, wc = w & 1;

  f32x4_t acc[2][2] = {};
  for (int c0 = 0; c0 < CC; c0 += 64) {
    {
      const int oi = tid >> 4, c4 = (tid & 15) * 4;
#pragma unroll
      for (int op = 0; op < 4; ++op) {
        const int o = op * 16 + oi;
        const float4 w4 = *(const float4*)&Wp[(size_t)(o0 + o) * CC + c0 + c4];
        bf16x4_t p;
        p[0] = (__bf16)w4.x; p[1] = (__bf16)w4.y;
        p[2] = (__bf16)w4.z; p[3] = (__bf16)w4.w;
        *(bf16x4_t*)&Ws[o * 72 + c4] = p;
      }
    }
    {
      const int t4 = (tid & 15) * 4, ci = tid >> 4;
#pragma unroll
      for (int cp = 0; cp < 4; ++cp) {
        const int c = cp * 16 + ci;
        const bf16x4_t x4 = *(const bf16x4_t*)&S[((size_t)b * CC + c0 + c) * TT + t0 + t4];
        Xs[(t4 + 0) * 72 + c] = x4[0];
        Xs[(t4 + 1) * 72 + c] = x4[1];
        Xs[(t4 + 2) * 72 + c] = x4[2];
        Xs[(t4 + 3) * 72 + c] = x4[3];
      }
    }
    __syncthreads();
#pragma unroll
    for (int kk = 0; kk < 2; ++kk) {
      bf16x8_t a[2], bb[2];
#pragma unroll
      for (int mm = 0; mm < 2; ++mm)
        a[mm] = *(const bf16x8_t*)&Ws[(wr * 32 + mm * 16 + sl) * 72 + kk * 32 + g * 8];
#pragma unroll
      for (int nn = 0; nn < 2; ++nn)
        bb[nn] = *(const bf16x8_t*)&Xs[(wc * 32 + nn * 16 + sl) * 72 + kk * 32 + g * 8];
#pragma unroll
      for (int mm = 0; mm < 2; ++mm)
#pragma unroll
        for (int nn = 0; nn < 2; ++nn)
          acc[mm][nn] = __builtin_amdgcn_mfma_f32_16x16x32_bf16(a[mm], bb[nn], acc[mm][nn], 0, 0, 0);
    }
    __syncthreads();
  }

  float* Cs = (float*)smem;
#pragma unroll
  for (int mm = 0; mm < 2; ++mm)
#pragma unroll
    for (int nn = 0; nn < 2; ++nn)
#pragma unroll
      for (int r = 0; r < 4; ++r)
        Cs[(wr * 32 + mm * 16 + 4 * g + r) * 68 + wc * 32 + nn * 16 + sl] = acc[mm][nn][r];
  __syncthreads();

  // fp32 store [o][t]
  const int o = tid >> 2, tq = tid & 3;
  const float bv_ = bp[o0 + o];
  float* dp = out + ((size_t)b * NCOUT + o0 + o) * TT + t0 + tq * 16;
#pragma unroll
  for (int i4 = 0; i4 < 4; ++i4) {
    f32x4_t v = *(const f32x4_t*)&Cs[o * 68 + tq * 16 + i4 * 4];
    v[0] += bv_; v[1] += bv_; v[2] += bv_; v[3] += bv_;
    *(f32x4_t*)(dp + i4 * 4) = v;
  }
}

// ===========================================================================
// K2 v2: MFMA attention, swapped QK^T (P^T register layout) + bpermute PV.
//   accT[t2] = mfma(A=K(row=s), B=Q(col=q)): lane holds q=lane&15,
//   s = sbase + t2*16 + 4*(lane>>4) + reg.
// ===========================================================================
__global__ __launch_bounds__(256) void attn_mfma2(
    const bf16* __restrict__ qw, const bf16* __restrict__ kw,
    const bf16* __restrict__ vtw,
    const float* __restrict__ wK, const float* __restrict__ wV,
    float* __restrict__ align_out, bf16* __restrict__ attnw) {
  const int q0 = blockIdx.x * 16;
  const int h  = blockIdx.y;
  const int b  = blockIdx.z;
  const int bh = b * HH + h;
  const int tid = threadIdx.x;
  const int w = tid >> 6, l = tid & 63, g = l >> 4, ql = l & 15;

  __shared__ float bandv[16][9];
  __shared__ float bandP[16][9];
  __shared__ float redbuf[4][16];
  __shared__ __align__(16) float stg[4][16][136];   // per-wave staging (34.8 KB)

  // phase A: band-K dots
  if (tid < 144) {
    const int q = tid / 9, j = tid % 9;
    const bf16* qrow = qw + ((size_t)bh * TT + q0 + q) * HD;
    const float* wkr = wK + j * HD;
    float s = 0.f;
#pragma unroll
    for (int d = 0; d < HD; ++d) s += bf2f(qrow[d]) * wkr[d];
    bandv[q][j] = s;
    bandP[q][j] = 0.f;
  }

  const bf16* qbase = qw + ((size_t)bh * TT + q0 + ql) * HD + g * 8;
  const bf16x8_t qa0 = *(const bf16x8_t*)(qbase);
  const bf16x8_t qa1 = *(const bf16x8_t*)(qbase + 32);
  __syncthreads();

  // phase B: QK^T (swapped: A=K so D rows = s, cols = q)
  f32x4_t accT[16];
#pragma unroll
  for (int t2 = 0; t2 < 16; ++t2) accT[t2] = (f32x4_t){0.f, 0.f, 0.f, 0.f};
  const int sbase = w * 256;
#pragma unroll
  for (int t2 = 0; t2 < 16; ++t2) {
    const bf16* kb = kw + ((size_t)bh * TT + sbase + t2 * 16 + ql) * HD + g * 8;
    const bf16x8_t k0 = *(const bf16x8_t*)(kb);
    const bf16x8_t k1 = *(const bf16x8_t*)(kb + 32);
    accT[t2] = __builtin_amdgcn_mfma_f32_16x16x32_bf16(k0, qa0, accT[t2], 0, 0, 0);
    accT[t2] = __builtin_amdgcn_mfma_f32_16x16x32_bf16(k1, qa1, accT[t2], 0, 0, 0);
  }

  // phase C: band bias + scale
#pragma unroll
  for (int t2 = 0; t2 < 16; ++t2) {
#pragma unroll
    for (int r = 0; r < 4; ++r) {
      const int s = sbase + t2 * 16 + 4 * g + r;
      float v2 = accT[t2][r];
      const int delta = s - (q0 + ql);
      if (delta >= -CLIPW && delta <= CLIPW) v2 += bandv[ql][delta + CLIPW];
      accT[t2][r] = v2 * 0.125f;
    }
  }

  // phase D: softmax stats (row = fixed q per lane)
  float mx = accT[0][0];
#pragma unroll
  for (int t2 = 0; t2 < 16; ++t2)
#pragma unroll
    for (int r = 0; r < 4; ++r) mx = fmaxf(mx, accT[t2][r]);
  mx = fmaxf(mx, __shfl_xor(mx, 16));
  mx = fmaxf(mx, __shfl_xor(mx, 32));
  if (l < 16) redbuf[w][l] = mx;
  __syncthreads();
  mx = fmaxf(fmaxf(redbuf[0][ql], redbuf[1][ql]),
             fmaxf(redbuf[2][ql], redbuf[3][ql]));

  float ssum = 0.f;
#pragma unroll
  for (int t2 = 0; t2 < 16; ++t2)
#pragma unroll
    for (int r = 0; r < 4; ++r) {
      const float e = __expf(accT[t2][r] - mx);
      accT[t2][r] = e;
      ssum += e;
    }
  ssum += __shfl_xor(ssum, 16);
  ssum += __shfl_xor(ssum, 32);
  __syncthreads();                 // everyone done reading max from redbuf
  if (l < 16) redbuf[w][l] = ssum;
  __syncthreads();
  const float inv = 1.0f / (redbuf[0][ql] + redbuf[1][ql] + redbuf[2][ql] + redbuf[3][ql]);

  // phase E: normalize in regs + stash band P
#pragma unroll
  for (int t2 = 0; t2 < 16; ++t2)
#pragma unroll
    for (int r = 0; r < 4; ++r) {
      const float p = accT[t2][r] * inv;
      accT[t2][r] = p;
      const int s = sbase + t2 * 16 + 4 * g + r;
      const int delta = s - (q0 + ql);
      if (delta >= -CLIPW && delta <= CLIPW) bandP[ql][delta + CLIPW] = p;
    }

  // phase F: alignments via per-wave LDS staging, coalesced float4 stores
  {
    const int q = l >> 2, c0 = l & 3;
#pragma unroll
    for (int hf = 0; hf < 2; ++hf) {
#pragma unroll
      for (int t2 = 0; t2 < 8; ++t2)
#pragma unroll
        for (int r = 0; r < 4; ++r)
          stg[w][ql][t2 * 16 + 4 * g + r] = accT[hf * 8 + t2][r];
      __asm__ volatile("s_waitcnt lgkmcnt(0)" ::: "memory");
      __builtin_amdgcn_sched_barrier(0);
      float* gp = align_out + ((size_t)bh * TT + q0 + q) * TT + sbase + hf * 128;
#pragma unroll
      for (int i = 0; i < 8; ++i) {
        const int c = (c0 + 4 * i) * 4;
        *(f32x4_t*)(gp + c) = *(const f32x4_t*)&stg[w][q][c];
      }
      __builtin_amdgcn_sched_barrier(0);
    }
  }

  // phase G: PV. Build A-frag (row=q, k=s-chunk) from accT via ds_bpermute.
  //   s_chunk = g*8+j -> src block = (g>>1), src reg = j&3,
  //   src lane = 16*(2*(g&1) + (j>>2)) + ql.
  f32x4_t oacc[4];
#pragma unroll
  for (int dt = 0; dt < 4; ++dt) oacc[dt] = (f32x4_t){0.f, 0.f, 0.f, 0.f};
  const int idxlo = (16 * (2 * (g & 1)) + ql) * 4;
  const int idxhi = idxlo + 64;
  const bool hiblk = (g >> 1);
#pragma unroll
  for (int cp = 0; cp < 8; ++cp) {
    bf16x8_t pa;
#pragma unroll
    for (int j = 0; j < 8; ++j) {
      const int r = j & 3;
      const int idx = (j < 4) ? idxlo : idxhi;
      const float v0 = __int_as_float(
          __builtin_amdgcn_ds_bpermute(idx, __float_as_int(accT[2 * cp][r])));
      const float v1 = __int_as_float(
          __builtin_amdgcn_ds_bpermute(idx, __float_as_int(accT[2 * cp + 1][r])));
      pa[j] = (__bf16)(hiblk ? v1 : v0);
    }
    const bf16* vb = vtw + ((size_t)bh * HD + ql) * TT + sbase + cp * 32 + g * 8;
#pragma unroll
    for (int dt = 0; dt < 4; ++dt) {
      const bf16x8_t vf = *(const bf16x8_t*)(vb + (size_t)dt * 16 * TT);
      oacc[dt] = __builtin_amdgcn_mfma_f32_16x16x32_bf16(pa, vf, oacc[dt], 0, 0, 0);
    }
  }

  // phase H: cross-wave PV reduce (reuse stg) + band-V bias + store attn
#pragma unroll
  for (int dt = 0; dt < 4; ++dt)
#pragma unroll
    for (int r = 0; r < 4; ++r)
      stg[w][4 * g + r][dt * 16 + ql] = oacc[dt][r];
  __syncthreads();

  const int q2 = tid & 15;
  const int d0 = tid >> 4;
#pragma unroll
  for (int rep = 0; rep < 4; ++rep) {
    const int d2 = d0 + rep * 16;
    float o = stg[0][q2][d2] + stg[1][q2][d2] + stg[2][q2][d2] + stg[3][q2][d2];
#pragma unroll
    for (int j = 0; j < 9; ++j) o += bandP[q2][j] * wV[j * HD + d2];
    attnw[((size_t)b * CC + h * HD + d2) * TT + q0 + q2] = __float2bfloat16(o);
  }
}

extern "C" void kernel_launch(void* const* d_in, const int* in_sizes, int n_in,
                              void* d_out, int out_size, void* d_ws, size_t ws_size,
                              hipStream_t stream) {
  const float* X  = (const float*)d_in[0];
  const float* Wq = (const float*)d_in[1];
  const float* bq = (const float*)d_in[2];
  const float* Wk = (const float*)d_in[3];
  const float* bk = (const float*)d_in[4];
  const float* Wv = (const float*)d_in[5];
  const float* bv = (const float*)d_in[6];
  const float* Wp = (const float*)d_in[7];
  const float* bp = (const float*)d_in[8];
  const float* wK = (const float*)d_in[9];
  const float* wV = (const float*)d_in[10];

  float* out       = (float*)d_out;
  float* align_out = out + (size_t)BB * NCOUT * TT;

  const size_t SZ = (size_t)BB * HH * TT * HD;   // 4,194,304 elems
  bf16* qw    = (bf16*)d_ws;                     // [b][h][t][d]
  bf16* kw    = qw + SZ;                         // [b][h][t][d]
  bf16* vtw   = qw + 2 * SZ;                     // [b][c][t]  (V^T)
  bf16* attnw = qw + 3 * SZ;                     // [b][c][t]

  gemm_qkv<<<dim3(TT / 64, 24, BB), 256, 0, stream>>>(
      X, Wq, bq, Wk, bk, Wv, bv, qw, kw, vtw);
  attn_mfma2<<<dim3(TT / 16, HH, BB), 256, 0, stream>>>(
      qw, kw, vtw, wK, wV, align_out, attnw);
  gemm_out<<<dim3(TT / 64, NCOUT / 64, BB), 256, 0, stream>>>(
      attnw, Wp, bp, out);
}